// Round 9
// baseline (250.695 us; speedup 1.0000x reference)
//
#include <hip/hip_runtime.h>
#include <hip/hip_bf16.h>

#define BB 8
#define NN 2048
#define FIN 128
#define FO 64
#define ALPHA 0.2f

typedef __attribute__((ext_vector_type(8))) short bf16x8;
typedef __attribute__((ext_vector_type(4))) float f32x4;
typedef __attribute__((ext_vector_type(4))) int i32x4;
typedef __attribute__((ext_vector_type(2))) unsigned long long u64x2;

__device__ inline short f2bf(float x) {
    unsigned u = __float_as_uint(x);
    u += 0x7fffu + ((u >> 16) & 1u);   // RNE, sign-agnostic, no NaN inputs here
    return (short)(u >> 16);
}

// ---------------- Kernel P: adj int32 -> bitmask (32x traffic cut) ----------
// adj carries 1 bit per 4 bytes.  Sequential sweep in the fill-like pattern
// (1KB contiguous per wave-instr): 134MB read + 4.2MB write ~= 23us at stream
// BW, vs ~50us the staged-gather attn paid.  Layout: unit U = 256 j's;
// word k (k=0..3), bit L = adj[256U + 4L + k]  (straight from 4 ballots of an
// i32x4-per-lane load).
__global__ __launch_bounds__(256) void pack_kernel(
    const int* __restrict__ adj, unsigned long long* __restrict__ ab)
{
    const int lane = threadIdx.x & 63;
    const int wid  = (blockIdx.x << 2) + (threadIdx.x >> 6);   // 4096 waves
    const int* src = adj + (size_t)wid * (32 * 256) + lane * 4;
#pragma unroll 4
    for (int c = 0; c < 32; c++) {
        i32x4 v = *(const i32x4*)(src + c * 256);
        unsigned long long b0 = __ballot(v[0] > 0);
        unsigned long long b1 = __ballot(v[1] > 0);
        unsigned long long b2 = __ballot(v[2] > 0);
        unsigned long long b3 = __ballot(v[3] > 0);
        if (lane == 0) {
            u64x2* d = (u64x2*)(ab + ((size_t)wid * 32 + c) * 4);
            u64x2 lo; lo[0] = b0; lo[1] = b1;
            u64x2 hi; hi[0] = b2; hi[1] = b3;
            d[0] = lo; d[1] = hi;
        }
    }
}

// ---------------- Kernel A: Wh = h@W; whF in MFMA B-fragment layout ----------
// whF[b][jc][ot][lane][8] shorts: lane L holds Wh[b][j=jc*32+(L>>4)*8+jj][o=ot*16+(L&15)]
// h rows are wave-uniform -> scalar (K$) loads; no LDS, no barrier.
// e2 maxes: ONE non-atomic float store per wave into e2p[b][0..255].
__global__ __launch_bounds__(256) void wh_kernel(
    const float* __restrict__ h, const float* __restrict__ W,
    const float* __restrict__ a, float* __restrict__ e1, float* __restrict__ e2,
    float* __restrict__ e2p, short* __restrict__ whF)
{
    const int t  = threadIdx.x;
    const int o  = t & 63;
    const int wv = t >> 6;                     // rows wv*8 .. wv*8+7
    const int r0 = blockIdx.x * 32;            // 32 rows per block (same batch)
    const float* __restrict__ hrow =
        h + (size_t)(r0 + __builtin_amdgcn_readfirstlane(wv) * 8) * FIN;

    float acc[8];
#pragma unroll
    for (int rr = 0; rr < 8; rr++) acc[rr] = 0.f;

    for (int f = 0; f < FIN; f += 4) {
        const float w0 = W[(f + 0) * FO + o];
        const float w1 = W[(f + 1) * FO + o];
        const float w2 = W[(f + 2) * FO + o];
        const float w3 = W[(f + 3) * FO + o];
#pragma unroll
        for (int rr = 0; rr < 8; rr++) {
            const float4 hv = *(const float4*)(hrow + rr * FIN + f);  // uniform -> SGPR
            acc[rr] = fmaf(hv.x, w0, acc[rr]);
            acc[rr] = fmaf(hv.y, w1, acc[rr]);
            acc[rr] = fmaf(hv.z, w2, acc[rr]);
            acc[rr] = fmaf(hv.w, w3, acc[rr]);
        }
    }

    const int b   = r0 / NN;
    const int ib0 = r0 - b * NN;
    const int ibb = ib0 + wv * 8;
    const int jc  = ibb >> 5;
    const int qq  = (ibb >> 3) & 3;
    const int ot  = o >> 4, mm = o & 15;
    const int L   = mm + qq * 16;
    bf16x8 frag;
#pragma unroll
    for (int rr = 0; rr < 8; rr++) frag[rr] = f2bf(acc[rr]);
    *(bf16x8*)(whF + ((((size_t)(b * 64 + jc) * 4 + ot) * 64 + L) * 8)) = frag;

    const float a1 = a[o], a2 = a[FO + o];
    float vmax = -3.0e38f;
#pragma unroll
    for (int rr = 0; rr < 8; rr++) {
        float v1 = acc[rr] * a1, v2 = acc[rr] * a2;
#pragma unroll
        for (int msk = 32; msk >= 1; msk >>= 1) {
            v1 += __shfl_xor(v1, msk, 64);
            v2 += __shfl_xor(v2, msk, 64);
        }
        vmax = fmaxf(vmax, v2);
        if (o == 0) { e1[r0 + wv * 8 + rr] = v1; e2[r0 + wv * 8 + rr] = v2; }
    }
    if (o == 0) e2p[b * 256 + (ib0 >> 5) * 4 + wv] = vmax;
}

// ---------------- Kernel B: attention from bitmask; barrier-free loop -------
// adj per block is now 16 rows x 256B = 4KB (L1-resident) -> no staging, no
// barriers, no gl_lds.  e2 (8KB/batch) and whF (256KB/batch) are L2-resident
// direct loads.  LDS only for the one-shot epilogue combine.
// Unpack (verified vs pack layout): j = tt*256 + col + jj, col = w*64+s2*32+q*8
// -> word k = jj&3, bit index = (col>>2) + (jj>>2).
struct SMemC { float comb[4][16][64]; float lsum[4][16]; float red4[4]; };

__global__ __launch_bounds__(256) void attn_kernel(
    const unsigned long long* __restrict__ ab, const float* __restrict__ e1,
    const float* __restrict__ e2, const float* __restrict__ e2p,
    const short* __restrict__ whF, float* __restrict__ out)
{
    __shared__ SMemC sm;
    const int t = threadIdx.x, w = t >> 6, lane = t & 63;
    const int m = lane & 15, q = lane >> 4;
    const int blk = blockIdx.x;
    const int b  = blk >> 7;
    const int i0 = (blk & 127) * 16;
    const int i  = i0 + m;

    // ---- batch e2max from per-wave partials (256 floats, L2-resident) ----
    float pv = e2p[b * 256 + t];
    const float e1v = e1[b * NN + i];
#pragma unroll
    for (int k = 32; k >= 1; k >>= 1) pv = fmaxf(pv, __shfl_xor(pv, k, 64));
    if (lane == 0) sm.red4[w] = pv;
    __syncthreads();
    const float e2mx = fmaxf(fmaxf(sm.red4[0], sm.red4[1]),
                             fmaxf(sm.red4[2], sm.red4[3]));

    float mi = e1v + e2mx;
    mi = mi > 0.f ? mi : ALPHA * mi;           // safe per-row max bound (leakyrelu monotone)

    const short* whFb = whF + (size_t)b * (64 * 4 * 64 * 8);
    const float* e2b = e2 + b * NN;
    const unsigned long long* abrow = ab + (size_t)(b * NN + i) * 32;  // row's 32 u64

    f32x4 acc0 = {0.f,0.f,0.f,0.f}, acc1 = acc0, acc2 = acc0, acc3 = acc0;
    float lsum = 0.f;

#pragma unroll
    for (int tt = 0; tt < 8; tt++) {
        u64x2 Ba = *(const u64x2*)(abrow + tt * 4);
        u64x2 Bb = *(const u64x2*)(abrow + tt * 4 + 2);
        const unsigned long long B0 = Ba[0], B1 = Ba[1], B2 = Bb[0], B3 = Bb[1];

#pragma unroll
        for (int s2 = 0; s2 < 2; s2++) {
            const int col = w * 64 + s2 * 32 + q * 8;   // 0..255 within tile
            const int sh = col >> 2;
            const unsigned long long C0 = B0 >> sh, C1 = B1 >> sh,
                                     C2 = B2 >> sh, C3 = B3 >> sh;

            f32x4 ev0 = *(const f32x4*)(e2b + tt * 256 + col);
            f32x4 ev1 = *(const f32x4*)(e2b + tt * 256 + col + 4);

            const int jc = tt * 8 + w * 2 + s2;
            const short* bfp = whFb + (size_t)jc * 2048 + lane * 8;
            bf16x8 b0 = *(const bf16x8*)(bfp);
            bf16x8 b1 = *(const bf16x8*)(bfp + 512);
            bf16x8 b2 = *(const bf16x8*)(bfp + 1024);
            bf16x8 b3 = *(const bf16x8*)(bfp + 1536);

            bf16x8 af;
#pragma unroll
            for (int jj = 0; jj < 8; jj++) {
                const unsigned long long Cw =
                    (jj & 3) == 0 ? C0 : (jj & 3) == 1 ? C1 : (jj & 3) == 2 ? C2 : C3;
                const bool av = (Cw >> (jj >> 2)) & 1ull;
                const float e2j = (jj < 4) ? ev0[jj] : ev1[jj - 4];
                float e = e1v + e2j;
                e = e > 0.f ? e : ALPHA * e;
                const float pe = av ? __expf(e - mi) : 0.f;
                lsum += pe;
                af[jj] = f2bf(pe);
            }

            acc0 = __builtin_amdgcn_mfma_f32_16x16x32_bf16(af, b0, acc0, 0, 0, 0);
            acc1 = __builtin_amdgcn_mfma_f32_16x16x32_bf16(af, b1, acc1, 0, 0, 0);
            acc2 = __builtin_amdgcn_mfma_f32_16x16x32_bf16(af, b2, acc2, 0, 0, 0);
            acc3 = __builtin_amdgcn_mfma_f32_16x16x32_bf16(af, b3, acc3, 0, 0, 0);
        }
    }

    // cross-wave combine in LDS (one-shot epilogue)
    lsum += __shfl_xor(lsum, 16, 64);
    lsum += __shfl_xor(lsum, 32, 64);
    if (q == 0) sm.lsum[w][m] = lsum;
#pragma unroll
    for (int ot = 0; ot < 4; ot++) {
        f32x4 av = (ot == 0) ? acc0 : (ot == 1) ? acc1 : (ot == 2) ? acc2 : acc3;
#pragma unroll
        for (int reg = 0; reg < 4; reg++)
            sm.comb[w][q * 4 + reg][ot * 16 + m] = av[reg];
    }
    __syncthreads();

    const int row = t >> 4, c0 = (t & 15) * 4;
    f32x4 sum = *(const f32x4*)&sm.comb[0][row][c0];
#pragma unroll
    for (int ww = 1; ww < 4; ww++) {
        f32x4 sv = *(const f32x4*)&sm.comb[ww][row][c0];
        sum.x += sv.x; sum.y += sv.y; sum.z += sv.z; sum.w += sv.w;
    }
    float l = sm.lsum[0][row] + sm.lsum[1][row] + sm.lsum[2][row] + sm.lsum[3][row];
    l = fmaxf(l, 1e-30f);
    const float rl = 1.f / l;
    float vr[4] = { sum.x * rl, sum.y * rl, sum.z * rl, sum.w * rl };
    f32x4 res;
#pragma unroll
    for (int kk = 0; kk < 4; kk++)
        res[kk] = vr[kk] > 0.f ? vr[kk] : (__expf(vr[kk]) - 1.f);
    *(f32x4*)&out[((size_t)(b * NN + i0 + row)) * FO + c0] = res;
}

extern "C" void kernel_launch(void* const* d_in, const int* in_sizes, int n_in,
                              void* d_out, int out_size, void* d_ws, size_t ws_size,
                              hipStream_t stream) {
    const float* h   = (const float*)d_in[0];
    const int*   adj = (const int*)d_in[1];
    const float* W   = (const float*)d_in[2];
    const float* a   = (const float*)d_in[3];
    float* out = (float*)d_out;

    char* ws = (char*)d_ws;
    short* whF = (short*)ws;                                   // 2 MB
    size_t off = (size_t)BB * 64 * 4 * 64 * 8 * sizeof(short);
    float* e1  = (float*)(ws + off);  off += (size_t)BB * NN * 4;
    float* e2  = (float*)(ws + off);  off += (size_t)BB * NN * 4;
    float* e2p = (float*)(ws + off);  off += (size_t)BB * 256 * 4;
    unsigned long long* adjbits = (unsigned long long*)(ws + off);  // 4 MB

    pack_kernel<<<1024, 256, 0, stream>>>(adj, adjbits);
    wh_kernel<<<(BB * NN) / 32, 256, 0, stream>>>(h, W, a, e1, e2, e2p, whF);
    attn_kernel<<<BB * (NN / 16), 256, 0, stream>>>(adjbits, e1, e2, e2p, whF, out);
}